// Round 1
// baseline (1115.903 us; speedup 1.0000x reference)
//
#include <hip/hip_runtime.h>
#include <math.h>

#define Bb 64
#define Ll 2048
#define Ff 100
#define Dd 1024
#define NC 50000
#define NBLK3 391   // ceil(50000/128)

// ---------------------------------------------------------------------------
// K1: pooled[b][d] = elu( max_l (x[b,l,:] . conv_w[d,:]) + conv_b[d] )
// grid(64, 8): blockIdx.x = b (XCD-swizzle: same-b d-tiles colocate per XCD),
//              blockIdx.y = dtile (128 d each). 256 threads, 8l x 8d per thread.
// conv_w tile in LDS, XOR-swizzled quads (2-way conflicts only). x from global
// (16 dt-lanes broadcast same address -> 4 distinct 16B segs/instr, L2-resident).
// ---------------------------------------------------------------------------
__global__ __launch_bounds__(256, 2)
void k1_conv_maxpool_elu(const float* __restrict__ x,
                         const float* __restrict__ conv_w,
                         const float* __restrict__ conv_b,
                         float* __restrict__ pooled)
{
    const int b     = blockIdx.x;
    const int dtile = blockIdx.y;
    const int tid   = threadIdx.x;
    const int lt    = tid >> 4;   // 0..15
    const int dt    = tid & 15;   // 0..15
    const int d0    = dtile * 128;

    __shared__ float wsm[128 * 128];   // [d][swizzled f-quad*4], stride 128 floats
    __shared__ float red[16][128];

    // stage conv_w tile: 128 rows x 25 f-quads, column = q ^ ((row>>3)&7)
    for (int i = tid; i < 128 * 25; i += 256) {
        int dl = i / 25;
        int q  = i % 25;
        int pq = q ^ ((dl >> 3) & 7);
        float4 v = *(const float4*)(conv_w + (size_t)(d0 + dl) * Ff + q * 4);
        *(float4*)(&wsm[dl * 128 + pq * 4]) = v;
    }
    __syncthreads();

    float maxacc[8];
    #pragma unroll
    for (int i = 0; i < 8; ++i) maxacc[i] = -INFINITY;

    const int   swz = dt & 7;                 // == ((dt*8+dd)>>3)&7 for dd<8
    const float* wb = &wsm[(dt * 8) * 128];

    for (int lwin = 0; lwin < 16; ++lwin) {
        const float* xp = x + ((size_t)b * Ll + lwin * 128 + lt * 8) * Ff;
        float acc[8][8];
        #pragma unroll
        for (int i = 0; i < 8; ++i)
            #pragma unroll
            for (int j = 0; j < 8; ++j) acc[i][j] = 0.f;

        #pragma unroll 2
        for (int q = 0; q < 25; ++q) {
            float4 xv[8];
            #pragma unroll
            for (int li = 0; li < 8; ++li)
                xv[li] = *(const float4*)(xp + li * Ff + q * 4);
            const int pq4 = (q ^ swz) * 4;
            #pragma unroll
            for (int dd = 0; dd < 8; ++dd) {
                float4 wv = *(const float4*)(wb + dd * 128 + pq4);
                #pragma unroll
                for (int li = 0; li < 8; ++li) {
                    acc[li][dd] = fmaf(xv[li].x, wv.x, acc[li][dd]);
                    acc[li][dd] = fmaf(xv[li].y, wv.y, acc[li][dd]);
                    acc[li][dd] = fmaf(xv[li].z, wv.z, acc[li][dd]);
                    acc[li][dd] = fmaf(xv[li].w, wv.w, acc[li][dd]);
                }
            }
        }
        #pragma unroll
        for (int dd = 0; dd < 8; ++dd)
            #pragma unroll
            for (int li = 0; li < 8; ++li)
                maxacc[dd] = fmaxf(maxacc[dd], acc[li][dd]);
    }

    #pragma unroll
    for (int dd = 0; dd < 8; ++dd) red[lt][dt * 8 + dd] = maxacc[dd];
    __syncthreads();
    if (tid < 128) {
        float m = red[0][tid];
        #pragma unroll
        for (int j = 1; j < 16; ++j) m = fmaxf(m, red[j][tid]);
        m += conv_b[d0 + tid];
        pooled[(size_t)b * Dd + d0 + tid] = (m > 0.f) ? m : expm1f(m);
    }
}

// ---------------------------------------------------------------------------
// K2: out2T[d][b] = relu(pooled[b,:] . lin_w[d,:] + lin_b[d]); normsq[b] += sum o^2
// grid(64,4), 256 threads; thread = one d. pooled row is block-uniform.
// ---------------------------------------------------------------------------
__global__ __launch_bounds__(256)
void k2_linear_relu(const float* __restrict__ pooled,
                    const float* __restrict__ lin_w,
                    const float* __restrict__ lin_b,
                    float* __restrict__ out2T,
                    float* __restrict__ normsq)
{
    const int b = blockIdx.x;
    const int d = blockIdx.y * 256 + threadIdx.x;
    const float* pr = pooled + (size_t)b * Dd;
    const float* wr = lin_w + (size_t)d * Dd;
    float acc = 0.f;
    #pragma unroll 4
    for (int q = 0; q < Dd / 4; ++q) {
        float4 w = *(const float4*)(wr + q * 4);
        float4 p = *(const float4*)(pr + q * 4);
        acc = fmaf(w.x, p.x, acc);
        acc = fmaf(w.y, p.y, acc);
        acc = fmaf(w.z, p.z, acc);
        acc = fmaf(w.w, p.w, acc);
    }
    float o = fmaxf(acc + lin_b[d], 0.f);
    out2T[(size_t)d * Bb + b] = o;

    float ss = o * o;
    #pragma unroll
    for (int off = 32; off; off >>= 1) ss += __shfl_xor(ss, off, 64);
    __shared__ float wsum[4];
    if ((threadIdx.x & 63) == 0) wsum[threadIdx.x >> 6] = ss;
    __syncthreads();
    if (threadIdx.x == 0)
        atomicAdd(&normsq[b], wsum[0] + wsum[1] + wsum[2] + wsum[3]);
}

// ---------------------------------------------------------------------------
// K3: e[b][n] = exp( (out2[b,:]/||out2[b]||) . embed[n,:] ), plus per-block
// partial sums over n for each b. grid(391): 128 concepts/block; 256 threads,
// thread tile = 8 concepts x 4 b. out2T (pre-scaled by 1/norm) staged in LDS.
// ---------------------------------------------------------------------------
__global__ __launch_bounds__(256)
void k3_logits_exp(const float* __restrict__ embed,
                   const float* __restrict__ out2T,
                   const float* __restrict__ normsq,
                   float* __restrict__ out,        // exp(logits), unscaled
                   float* __restrict__ partials)   // [NBLK3][64]
{
    const int tid = threadIdx.x;
    const int nt  = tid & 15;    // 0..15 -> 8 concepts each
    const int bt  = tid >> 4;    // 0..15 -> 4 b each
    const int n0  = blockIdx.x * 128;

    __shared__ float xs[128][64];
    __shared__ float tsm[64];
    if (tid < 64) tsm[tid] = 1.f / fmaxf(sqrtf(normsq[tid]), 1e-12f);

    const int nbase = n0 + nt * 8;
    const float* hrow[8];
    bool valid[8];
    #pragma unroll
    for (int i = 0; i < 8; ++i) {
        int n = nbase + i;
        valid[i] = (n < NC);
        hrow[i] = embed + (size_t)(valid[i] ? n : 0) * Dd;
    }

    float acc[8][4];
    #pragma unroll
    for (int i = 0; i < 8; ++i)
        #pragma unroll
        for (int j = 0; j < 4; ++j) acc[i][j] = 0.f;

    for (int fc = 0; fc < 8; ++fc) {
        __syncthreads();
        for (int i = tid; i < 128 * 16; i += 256) {
            int f = i >> 4, bq = i & 15;
            float4 v = *(const float4*)(out2T + (size_t)(fc * 128 + f) * Bb + bq * 4);
            v.x *= tsm[bq * 4 + 0];
            v.y *= tsm[bq * 4 + 1];
            v.z *= tsm[bq * 4 + 2];
            v.w *= tsm[bq * 4 + 3];
            *(float4*)(&xs[f][bq * 4]) = v;
        }
        __syncthreads();
        #pragma unroll 1
        for (int q = 0; q < 32; ++q) {
            float4 h[8];
            #pragma unroll
            for (int i = 0; i < 8; ++i)
                h[i] = *(const float4*)(hrow[i] + fc * 128 + q * 4);
            #pragma unroll
            for (int j = 0; j < 4; ++j) {
                float4 xv = *(const float4*)(&xs[q * 4 + j][bt * 4]);
                #pragma unroll
                for (int i = 0; i < 8; ++i) {
                    float hv = (j == 0) ? h[i].x : (j == 1) ? h[i].y
                             : (j == 2) ? h[i].z : h[i].w;
                    acc[i][0] = fmaf(hv, xv.x, acc[i][0]);
                    acc[i][1] = fmaf(hv, xv.y, acc[i][1]);
                    acc[i][2] = fmaf(hv, xv.z, acc[i][2]);
                    acc[i][3] = fmaf(hv, xv.w, acc[i][3]);
                }
            }
        }
    }

    float s[4] = {0.f, 0.f, 0.f, 0.f};
    #pragma unroll
    for (int i = 0; i < 8; ++i) {
        if (valid[i]) {
            int n = nbase + i;
            #pragma unroll
            for (int bi = 0; bi < 4; ++bi) {
                float e = expf(acc[i][bi]);
                out[(size_t)(bt * 4 + bi) * NC + n] = e;
                s[bi] += e;
            }
        }
    }
    // reduce across the 16 nt lanes (lane bits 0..3 within the wave)
    #pragma unroll
    for (int off = 1; off < 16; off <<= 1) {
        #pragma unroll
        for (int bi = 0; bi < 4; ++bi) s[bi] += __shfl_xor(s[bi], off, 64);
    }
    if (nt == 0) {
        #pragma unroll
        for (int bi = 0; bi < 4; ++bi)
            partials[(size_t)blockIdx.x * 64 + bt * 4 + bi] = s[bi];
    }
}

// ---------------------------------------------------------------------------
// K3b: rsum[b] = 1 / sum_k partials[k][b]
// ---------------------------------------------------------------------------
__global__ void k3b_reduce(const float* __restrict__ partials,
                           float* __restrict__ rsum)
{
    const int b = threadIdx.x;   // 64 threads, 1 block
    float s0 = 0.f, s1 = 0.f, s2 = 0.f, s3 = 0.f;
    int k = 0;
    for (; k + 4 <= NBLK3; k += 4) {
        s0 += partials[(size_t)(k + 0) * 64 + b];
        s1 += partials[(size_t)(k + 1) * 64 + b];
        s2 += partials[(size_t)(k + 2) * 64 + b];
        s3 += partials[(size_t)(k + 3) * 64 + b];
    }
    for (; k < NBLK3; ++k) s0 += partials[(size_t)k * 64 + b];
    rsum[b] = 1.f / (s0 + s1 + s2 + s3);
}

// ---------------------------------------------------------------------------
// K4: out[b][n] *= rsum[b]
// ---------------------------------------------------------------------------
__global__ __launch_bounds__(256)
void k4_scale(float* __restrict__ out, const float* __restrict__ rsum)
{
    const int b  = blockIdx.y;
    const int n4 = (blockIdx.x * 256 + threadIdx.x) * 4;
    if (n4 >= NC) return;
    const float r = rsum[b];
    float4* p = (float4*)(out + (size_t)b * NC + n4);
    float4 v = *p;
    v.x *= r; v.y *= r; v.z *= r; v.w *= r;
    *p = v;
}

extern "C" void kernel_launch(void* const* d_in, const int* in_sizes, int n_in,
                              void* d_out, int out_size, void* d_ws, size_t ws_size,
                              hipStream_t stream)
{
    const float* x      = (const float*)d_in[0];
    const float* embed  = (const float*)d_in[1];
    const float* conv_w = (const float*)d_in[2];
    const float* conv_b = (const float*)d_in[3];
    const float* lin_w  = (const float*)d_in[4];
    const float* lin_b  = (const float*)d_in[5];
    float* out = (float*)d_out;
    float* ws  = (float*)d_ws;

    float* out2T    = ws;               // 1024*64   = 65536 floats
    float* pooled   = ws + 65536;       // 64*1024   = 65536
    float* normsq   = ws + 131072;      // 64
    float* partials = ws + 131136;      // 391*64    = 25024
    float* rsum     = ws + 156160;      // 64        (total 625 KB)

    hipMemsetAsync(normsq, 0, 64 * sizeof(float), stream);

    k1_conv_maxpool_elu<<<dim3(64, 8), 256, 0, stream>>>(x, conv_w, conv_b, pooled);
    k2_linear_relu<<<dim3(64, 4), 256, 0, stream>>>(pooled, lin_w, lin_b, out2T, normsq);
    k3_logits_exp<<<dim3(NBLK3), 256, 0, stream>>>(embed, out2T, normsq, out, partials);
    k3b_reduce<<<dim3(1), 64, 0, stream>>>(partials, rsum);
    k4_scale<<<dim3(49, 64), 256, 0, stream>>>(out, rsum);
}

// Round 2
// 546.630 us; speedup vs baseline: 2.0414x; 2.0414x over previous
//
#include <hip/hip_runtime.h>
#include <hip/hip_bf16.h>
#include <math.h>

#define Bb 64
#define Ll 2048
#define Ff 100
#define Dd 1024
#define NC 50000
#define NBLK3 782   // ceil(50000/64)

typedef __attribute__((ext_vector_type(8))) short short8;
typedef __attribute__((ext_vector_type(4))) float floatx4;

union frag_u { short8 s8; unsigned u[4]; };

__device__ __forceinline__ unsigned cvt2bf(float x, float y) {
    __hip_bfloat162 h = __float22bfloat162_rn(make_float2(x, y));
    unsigned r; __builtin_memcpy(&r, &h, 4); return r;
}

// order-preserving float -> uint map (for atomicMax-based pooling)
__device__ __forceinline__ unsigned encf(float f) {
    unsigned u = __float_as_uint(f);
    return (u & 0x80000000u) ? ~u : (u | 0x80000000u);
}

// ---------------------------------------------------------------------------
// K1: z[b,l,d] = x[b,l,:] . conv_w[d,:]  via bf16 MFMA 16x16x32 (K=100 pad 128)
// block = (b, lwin of 128 l), 256 thr = 4 waves; per dc-loop chunk 128 d,
// wave covers 32 d (2 n-subtiles), 8 m-subtiles. x staged bf16 in LDS
// (row stride 136 -> 2-way banks, free). conv_w streamed (L2-hot).
// maxpool over l fused: cross-lwin via atomicMax on encoded uint.
// ---------------------------------------------------------------------------
__global__ __launch_bounds__(256, 1)
void k1_conv_mfma(const float* __restrict__ x,
                  const float* __restrict__ conv_w,
                  unsigned* __restrict__ pooled_enc)
{
    const int b    = blockIdx.x;
    const int lw   = blockIdx.y;
    const int tid  = threadIdx.x;
    const int wave = tid >> 6, lane = tid & 63;
    const int quad = lane >> 4, col = lane & 15;

    __shared__ unsigned short xs[128 * 136];

    // stage x[b, lw*128 .. +127][0..99] -> bf16, zero-pad f=100..135
    const float* xbase = x + ((size_t)b * Ll + (size_t)lw * 128) * Ff;
    for (int i = tid; i < 128 * 25; i += 256) {
        int r = i / 25, q = i % 25;
        float4 v = *(const float4*)(xbase + r * Ff + q * 4);
        unsigned* p = (unsigned*)&xs[r * 136 + q * 4];
        p[0] = cvt2bf(v.x, v.y);
        p[1] = cvt2bf(v.z, v.w);
    }
    for (int i = tid; i < 128 * 18; i += 256) {
        int r = i / 18, c = i % 18;
        *(unsigned*)&xs[r * 136 + 100 + c * 2] = 0u;
    }
    __syncthreads();

    const floatx4 zz = {0.f, 0.f, 0.f, 0.f};

    #pragma unroll 1
    for (int dc = 0; dc < 8; ++dc) {
        const int n0 = dc * 128 + wave * 32;
        floatx4 acc[8][2];
        #pragma unroll
        for (int s = 0; s < 8; ++s) { acc[s][0] = zz; acc[s][1] = zz; }

        #pragma unroll
        for (int kc = 0; kc < 4; ++kc) {
            const int f0 = kc * 32 + quad * 8;
            frag_u bf[2];
            #pragma unroll
            for (int t = 0; t < 2; ++t) {
                const int d = n0 + t * 16 + col;
                const float* wr = conv_w + (size_t)d * Ff;
                if (kc < 3) {
                    float4 b0 = *(const float4*)(wr + f0);
                    float4 b1 = *(const float4*)(wr + f0 + 4);
                    bf[t].u[0] = cvt2bf(b0.x, b0.y);
                    bf[t].u[1] = cvt2bf(b0.z, b0.w);
                    bf[t].u[2] = cvt2bf(b1.x, b1.y);
                    bf[t].u[3] = cvt2bf(b1.z, b1.w);
                } else {
                    if (quad == 0) {
                        float4 b0 = *(const float4*)(wr + 96);
                        bf[t].u[0] = cvt2bf(b0.x, b0.y);
                        bf[t].u[1] = cvt2bf(b0.z, b0.w);
                    } else { bf[t].u[0] = 0u; bf[t].u[1] = 0u; }
                    bf[t].u[2] = 0u; bf[t].u[3] = 0u;
                }
            }
            #pragma unroll
            for (int s = 0; s < 8; ++s) {
                frag_u af;
                af.s8 = *(const short8*)&xs[(s * 16 + col) * 136 + f0];
                acc[s][0] = __builtin_amdgcn_mfma_f32_16x16x32_bf16(
                    af.s8, bf[0].s8, acc[s][0], 0, 0, 0);
                acc[s][1] = __builtin_amdgcn_mfma_f32_16x16x32_bf16(
                    af.s8, bf[1].s8, acc[s][1], 0, 0, 0);
            }
        }

        // maxpool over this block's 128 l rows, then cross-block atomicMax
        #pragma unroll
        for (int t = 0; t < 2; ++t) {
            float m = -INFINITY;
            #pragma unroll
            for (int s = 0; s < 8; ++s)
                #pragma unroll
                for (int r = 0; r < 4; ++r) m = fmaxf(m, acc[s][t][r]);
            m = fmaxf(m, __shfl_xor(m, 16, 64));
            m = fmaxf(m, __shfl_xor(m, 32, 64));
            if (quad == 0) {
                const int d = n0 + t * 16 + col;
                atomicMax(&pooled_enc[(size_t)b * Dd + d], encf(m));
            }
        }
    }
}

// ---------------------------------------------------------------------------
// K1b: decode encoded max, + conv_b, elu  (in-place: uint -> float)
// ---------------------------------------------------------------------------
__global__ __launch_bounds__(256)
void k1b_decode(unsigned* __restrict__ pooled_enc,
                const float* __restrict__ conv_b)
{
    const int i = blockIdx.x * 256 + threadIdx.x;   // 65536 total
    unsigned e = pooled_enc[i];
    unsigned ub = (e & 0x80000000u) ? (e ^ 0x80000000u) : ~e;
    float m = __uint_as_float(ub) + conv_b[i & (Dd - 1)];
    ((float*)pooled_enc)[i] = (m > 0.f) ? m : expm1f(m);
}

// ---------------------------------------------------------------------------
// K2: out2[b][d] = relu(pooled[b,:] . lin_w[d,:] + lin_b[d]); normsq[b] += o^2
// grid(64,16): block = (b, 64-d tile); 4 lanes per dot product.
// ---------------------------------------------------------------------------
__global__ __launch_bounds__(256)
void k2_linear(const float* __restrict__ pooled,
               const float* __restrict__ lin_w,
               const float* __restrict__ lin_b,
               float* __restrict__ out2,
               float* __restrict__ normsq)
{
    const int b = blockIdx.x;
    const int tid = threadIdx.x, lane = tid & 63;
    const int d = blockIdx.y * 64 + (tid >> 2);
    const int kq = tid & 3;
    const float* pr = pooled + (size_t)b * Dd + kq * 256;
    const float* wr = lin_w + (size_t)d * Dd + kq * 256;
    float acc = 0.f;
    #pragma unroll 8
    for (int i = 0; i < 64; ++i) {
        float4 w = *(const float4*)(wr + i * 4);
        float4 p = *(const float4*)(pr + i * 4);
        acc = fmaf(w.x, p.x, fmaf(w.y, p.y, fmaf(w.z, p.z, fmaf(w.w, p.w, acc))));
    }
    acc += __shfl_xor(acc, 1, 64);
    acc += __shfl_xor(acc, 2, 64);
    float o = 0.f;
    if (kq == 0) {
        o = fmaxf(acc + lin_b[d], 0.f);
        out2[(size_t)b * Dd + d] = o;
    }
    float ss = o * o;
    ss += __shfl_xor(ss, 4, 64);  ss += __shfl_xor(ss, 8, 64);
    ss += __shfl_xor(ss, 16, 64); ss += __shfl_xor(ss, 32, 64);
    if (lane == 0) atomicAdd(&normsq[b], ss);
}

// ---------------------------------------------------------------------------
// K2b: xnbf[b][d] = bf16( out2[b][d] / max(||out2[b]||, eps) )
// ---------------------------------------------------------------------------
__global__ __launch_bounds__(256)
void k2b_norm_cvt(const float* __restrict__ out2,
                  const float* __restrict__ normsq,
                  unsigned short* __restrict__ xnbf)
{
    const int b = blockIdx.x, tid = threadIdx.x;
    const float r = 1.f / fmaxf(sqrtf(normsq[b]), 1e-12f);
    float4 v = *(const float4*)(out2 + (size_t)b * Dd + tid * 4);
    unsigned* p = (unsigned*)(xnbf + (size_t)b * Dd + tid * 4);
    p[0] = cvt2bf(v.x * r, v.y * r);
    p[1] = cvt2bf(v.z * r, v.w * r);
}

// ---------------------------------------------------------------------------
// K3: e[b][n] = exp(xn[b,:] . embed[n,:]) via bf16 MFMA, LDS-free.
// grid(782): 64 n per block; wave = 16 n (1 n-subtile), 4 m-subtiles (64 b).
// B-frag = 8 consecutive k of one embed row (2x fp32 dwordx4 + cvt).
// A-frag = 16B bf16 load from xnbf (L2-hot, 128 KB).
// ---------------------------------------------------------------------------
__global__ __launch_bounds__(256, 1)
void k3_logits_mfma(const float* __restrict__ embed,
                    const unsigned short* __restrict__ xnbf,
                    float* __restrict__ out,
                    float* __restrict__ partials)
{
    const int tid  = threadIdx.x;
    const int wave = tid >> 6, lane = tid & 63;
    const int quad = lane >> 4, col = lane & 15;
    const int n  = blockIdx.x * 64 + wave * 16 + col;
    const int ncl = n < NC ? n : NC - 1;
    const float* hrow = embed + (size_t)ncl * Dd;

    const floatx4 zz = {0.f, 0.f, 0.f, 0.f};
    floatx4 acc[4] = {zz, zz, zz, zz};

    #pragma unroll 2
    for (int k0 = 0; k0 < Dd; k0 += 32) {
        const int f0 = k0 + quad * 8;
        float4 b0 = *(const float4*)(hrow + f0);
        float4 b1 = *(const float4*)(hrow + f0 + 4);
        frag_u bf;
        bf.u[0] = cvt2bf(b0.x, b0.y);
        bf.u[1] = cvt2bf(b0.z, b0.w);
        bf.u[2] = cvt2bf(b1.x, b1.y);
        bf.u[3] = cvt2bf(b1.z, b1.w);
        #pragma unroll
        for (int s = 0; s < 4; ++s) {
            frag_u af;
            af.s8 = *(const short8*)(xnbf + (size_t)(s * 16 + col) * Dd + f0);
            acc[s] = __builtin_amdgcn_mfma_f32_16x16x32_bf16(
                af.s8, bf.s8, acc[s], 0, 0, 0);
        }
    }

    __shared__ float bpart[4][64];
    const bool vn = (n < NC);
    float e[4][4];
    #pragma unroll
    for (int s = 0; s < 4; ++s)
        #pragma unroll
        for (int r = 0; r < 4; ++r) {
            float v = vn ? __expf(acc[s][r]) : 0.f;
            e[s][r] = v;
            if (vn) out[(size_t)(s * 16 + quad * 4 + r) * NC + n] = v;
        }
    #pragma unroll
    for (int s = 0; s < 4; ++s)
        #pragma unroll
        for (int r = 0; r < 4; ++r) {
            float v = e[s][r];
            v += __shfl_xor(v, 1, 64); v += __shfl_xor(v, 2, 64);
            v += __shfl_xor(v, 4, 64); v += __shfl_xor(v, 8, 64);
            if (col == 0) bpart[wave][s * 16 + quad * 4 + r] = v;
        }
    __syncthreads();
    if (tid < 64)
        partials[(size_t)blockIdx.x * 64 + tid] =
            bpart[0][tid] + bpart[1][tid] + bpart[2][tid] + bpart[3][tid];
}

// ---------------------------------------------------------------------------
// K3b: rsum[b] = 1 / sum_k partials[k][b]
// ---------------------------------------------------------------------------
__global__ void k3b_reduce(const float* __restrict__ partials,
                           float* __restrict__ rsum)
{
    const int b = threadIdx.x;   // 64 threads, 1 block
    float s0 = 0.f, s1 = 0.f, s2 = 0.f, s3 = 0.f;
    int k = 0;
    for (; k + 4 <= NBLK3; k += 4) {
        s0 += partials[(size_t)(k + 0) * 64 + b];
        s1 += partials[(size_t)(k + 1) * 64 + b];
        s2 += partials[(size_t)(k + 2) * 64 + b];
        s3 += partials[(size_t)(k + 3) * 64 + b];
    }
    for (; k < NBLK3; ++k) s0 += partials[(size_t)k * 64 + b];
    rsum[b] = 1.f / (s0 + s1 + s2 + s3);
}

// ---------------------------------------------------------------------------
// K4: out[b][n] *= rsum[b]
// ---------------------------------------------------------------------------
__global__ __launch_bounds__(256)
void k4_scale(float* __restrict__ out, const float* __restrict__ rsum)
{
    const int b  = blockIdx.y;
    const int n4 = (blockIdx.x * 256 + threadIdx.x) * 4;
    if (n4 >= NC) return;
    const float r = rsum[b];
    float4* p = (float4*)(out + (size_t)b * NC + n4);
    float4 v = *p;
    v.x *= r; v.y *= r; v.z *= r; v.w *= r;
    *p = v;
}

extern "C" void kernel_launch(void* const* d_in, const int* in_sizes, int n_in,
                              void* d_out, int out_size, void* d_ws, size_t ws_size,
                              hipStream_t stream)
{
    const float* x      = (const float*)d_in[0];
    const float* embed  = (const float*)d_in[1];
    const float* conv_w = (const float*)d_in[2];
    const float* conv_b = (const float*)d_in[3];
    const float* lin_w  = (const float*)d_in[4];
    const float* lin_b  = (const float*)d_in[5];
    float* out = (float*)d_out;
    float* ws  = (float*)d_ws;

    unsigned* pooled_enc = (unsigned*)ws;              // 65536 u32 (aliased fp32 after k1b)
    float*    pooled     = (float*)ws;
    float*    normsq     = ws + 65536;                 // 64
    float*    out2       = ws + 65536 + 64;            // 65536
    unsigned short* xnbf = (unsigned short*)(ws + 131136); // 65536 bf16 (=32768 f)
    float*    partials   = ws + 131136 + 32768;        // 782*64 = 50048
    float*    rsum       = ws + 213952;                // 64  (total ~856 KB)

    hipMemsetAsync(ws, 0, (65536 + 64) * sizeof(float), stream); // pooled_enc + normsq

    k1_conv_mfma<<<dim3(64, 16), 256, 0, stream>>>(x, conv_w, pooled_enc);
    k1b_decode<<<dim3(256), 256, 0, stream>>>(pooled_enc, conv_b);
    k2_linear<<<dim3(64, 16), 256, 0, stream>>>(pooled, lin_w, lin_b, out2, normsq);
    k2b_norm_cvt<<<dim3(64), 256, 0, stream>>>(out2, normsq, xnbf);
    k3_logits_mfma<<<dim3(NBLK3), 256, 0, stream>>>(embed, xnbf, out, partials);
    k3b_reduce<<<dim3(1), 64, 0, stream>>>(partials, rsum);
    k4_scale<<<dim3(49, 64), 256, 0, stream>>>(out, rsum);
}

// Round 3
// 528.427 us; speedup vs baseline: 2.1117x; 1.0344x over previous
//
#include <hip/hip_runtime.h>
#include <hip/hip_bf16.h>
#include <math.h>

#define Bb 64
#define Ll 2048
#define Ff 100
#define Dd 1024
#define NC 50000
#define NBLK3 782   // ceil(50000/64)

typedef __attribute__((ext_vector_type(8))) short short8;
typedef __attribute__((ext_vector_type(4))) float floatx4;

union frag_u { short8 s8; unsigned u[4]; };

__device__ __forceinline__ unsigned cvt2bf(float x, float y) {
    __hip_bfloat162 h = __float22bfloat162_rn(make_float2(x, y));
    unsigned r; __builtin_memcpy(&r, &h, 4); return r;
}

// ---------------------------------------------------------------------------
// K1: pooled[b][d] = elu( max_l (x[b,l,:] . conv_w[d,:]) + conv_b[d] )
// grid(64 b, 4 dgroup): block owns 256 d and ALL l. conv_w bf16 fragments
// resident in registers (wave = 64 d x full K=128pad: 64 VGPR). x streamed
// in 64-l windows through double-buffered LDS (contiguous 25.6 KB per window
// -> perfectly coalesced). Max over l accumulated in registers; no atomics.
// ---------------------------------------------------------------------------
__global__ __launch_bounds__(256, 1)
void k1_conv_mfma(const float* __restrict__ x,
                  const float* __restrict__ conv_w,
                  const float* __restrict__ conv_b,
                  float* __restrict__ pooled)
{
    const int b     = blockIdx.x;
    const int dbase = blockIdx.y << 8;
    const int tid   = threadIdx.x;
    const int wave  = tid >> 6, lane = tid & 63;
    const int quad  = lane >> 4, col = lane & 15;

    __shared__ __align__(16) unsigned short xs[2][64 * 136];

    // zero the k-pad (cols 100..127) once, both buffers
    for (int i = tid; i < 64 * 14 * 2; i += 256) {
        int bu = i / (64 * 14), r = i % (64 * 14);
        int row = r / 14, c = r % 14;
        *(unsigned*)&xs[bu][row * 136 + 100 + c * 2] = 0u;
    }

    // conv_w fragments -> registers (once per block)
    frag_u breg[4][4];
    #pragma unroll
    for (int t = 0; t < 4; ++t) {
        const int d = dbase + wave * 64 + t * 16 + col;
        const float* wr = conv_w + (size_t)d * Ff;
        #pragma unroll
        for (int kc = 0; kc < 3; ++kc) {
            float4 p0 = *(const float4*)(wr + kc * 32 + quad * 8);
            float4 p1 = *(const float4*)(wr + kc * 32 + quad * 8 + 4);
            breg[t][kc].u[0] = cvt2bf(p0.x, p0.y);
            breg[t][kc].u[1] = cvt2bf(p0.z, p0.w);
            breg[t][kc].u[2] = cvt2bf(p1.x, p1.y);
            breg[t][kc].u[3] = cvt2bf(p1.z, p1.w);
        }
        if (quad == 0) {
            float4 p0 = *(const float4*)(wr + 96);
            breg[t][3].u[0] = cvt2bf(p0.x, p0.y);
            breg[t][3].u[1] = cvt2bf(p0.z, p0.w);
        } else { breg[t][3].u[0] = 0u; breg[t][3].u[1] = 0u; }
        breg[t][3].u[2] = 0u; breg[t][3].u[3] = 0u;
    }

    float m[4] = {-INFINITY, -INFINITY, -INFINITY, -INFINITY};

    // stage window 0
    {
        const float* xw = x + (size_t)b * Ll * Ff;
        #pragma unroll
        for (int j = 0; j < 7; ++j) {
            int idx = tid + j * 256;
            if (idx < 1600) {
                float4 v = *(const float4*)(xw + idx * 4);
                int row = idx / 25, c4 = idx % 25;
                uint2 w2 = make_uint2(cvt2bf(v.x, v.y), cvt2bf(v.z, v.w));
                *(uint2*)&xs[0][row * 136 + c4 * 4] = w2;
            }
        }
    }
    __syncthreads();

    for (int w = 0; w < 32; ++w) {
        const int cur = w & 1;
        float4 xv[7];
        if (w < 31) {   // issue next window's loads before compute
            const float* xw = x + ((size_t)b * Ll + (size_t)(w + 1) * 64) * Ff;
            #pragma unroll
            for (int j = 0; j < 7; ++j) {
                int idx = tid + j * 256;
                if (idx < 1600) xv[j] = *(const float4*)(xw + idx * 4);
            }
        }

        floatx4 acc[4][4];
        const floatx4 zz = {0.f, 0.f, 0.f, 0.f};
        #pragma unroll
        for (int s = 0; s < 4; ++s)
            #pragma unroll
            for (int t = 0; t < 4; ++t) acc[s][t] = zz;

        #pragma unroll
        for (int kc = 0; kc < 4; ++kc) {
            frag_u af[4];
            #pragma unroll
            for (int s = 0; s < 4; ++s)
                af[s].s8 = *(const short8*)&xs[cur][(s * 16 + col) * 136 + kc * 32 + quad * 8];
            #pragma unroll
            for (int s = 0; s < 4; ++s)
                #pragma unroll
                for (int t = 0; t < 4; ++t)
                    acc[s][t] = __builtin_amdgcn_mfma_f32_16x16x32_bf16(
                        af[s].s8, breg[t][kc].s8, acc[s][t], 0, 0, 0);
        }

        #pragma unroll
        for (int t = 0; t < 4; ++t)
            #pragma unroll
            for (int s = 0; s < 4; ++s)
                #pragma unroll
                for (int r = 0; r < 4; ++r)
                    m[t] = fmaxf(m[t], acc[s][t][r]);

        if (w < 31) {
            #pragma unroll
            for (int j = 0; j < 7; ++j) {
                int idx = tid + j * 256;
                if (idx < 1600) {
                    int row = idx / 25, c4 = idx % 25;
                    uint2 w2 = make_uint2(cvt2bf(xv[j].x, xv[j].y), cvt2bf(xv[j].z, xv[j].w));
                    *(uint2*)&xs[cur ^ 1][row * 136 + c4 * 4] = w2;
                }
            }
            __syncthreads();
        }
    }

    #pragma unroll
    for (int t = 0; t < 4; ++t) {
        float mm = m[t];
        mm = fmaxf(mm, __shfl_xor(mm, 16, 64));
        mm = fmaxf(mm, __shfl_xor(mm, 32, 64));
        if (quad == 0) {
            const int d = dbase + wave * 64 + t * 16 + col;
            float v = mm + conv_b[d];
            pooled[(size_t)b * Dd + d] = (v > 0.f) ? v : expm1f(v);
        }
    }
}

// ---------------------------------------------------------------------------
// K2: out2[b][d] = relu(pooled[b,:] . lin_w[d,:] + lin_b[d]); normsq[b] += o^2
// grid(4096) = 64 b x 64 dtiles of 16 d. 16 k-lanes per dot, lane-contiguous
// 256 B global segments (coalesced).
// ---------------------------------------------------------------------------
__global__ __launch_bounds__(256)
void k2_linear(const float* __restrict__ pooled,
               const float* __restrict__ lin_w,
               const float* __restrict__ lin_b,
               float* __restrict__ out2,
               float* __restrict__ normsq)
{
    const int bx = blockIdx.x;
    const int b = bx >> 6, dt = bx & 63;
    const int tid = threadIdx.x;
    const int dl = tid >> 4, kq = tid & 15;
    const int d = dt * 16 + dl;
    const float* wr = lin_w + (size_t)d * Dd;
    const float* pr = pooled + (size_t)b * Dd;
    float acc = 0.f;
    #pragma unroll
    for (int i = 0; i < 16; ++i) {
        const int off = i * 64 + kq * 4;
        float4 wv = *(const float4*)(wr + off);
        float4 pv = *(const float4*)(pr + off);
        acc = fmaf(wv.x, pv.x, fmaf(wv.y, pv.y, fmaf(wv.z, pv.z, fmaf(wv.w, pv.w, acc))));
    }
    acc += __shfl_xor(acc, 1, 64);
    acc += __shfl_xor(acc, 2, 64);
    acc += __shfl_xor(acc, 4, 64);
    acc += __shfl_xor(acc, 8, 64);
    float ss = 0.f;
    if (kq == 0) {
        float o = fmaxf(acc + lin_b[d], 0.f);
        out2[(size_t)b * Dd + d] = o;
        ss = o * o;
    }
    ss += __shfl_xor(ss, 16, 64);
    ss += __shfl_xor(ss, 32, 64);
    __shared__ float wsum[4];
    if ((tid & 63) == 0) wsum[tid >> 6] = ss;
    __syncthreads();
    if (tid == 0)
        atomicAdd(&normsq[b], wsum[0] + wsum[1] + wsum[2] + wsum[3]);
}

// ---------------------------------------------------------------------------
// K2b: xnbf[b][d] = bf16( out2[b][d] / max(||out2[b]||, eps) )
// ---------------------------------------------------------------------------
__global__ __launch_bounds__(256)
void k2b_norm_cvt(const float* __restrict__ out2,
                  const float* __restrict__ normsq,
                  unsigned short* __restrict__ xnbf)
{
    const int b = blockIdx.x, tid = threadIdx.x;
    const float r = 1.f / fmaxf(sqrtf(normsq[b]), 1e-12f);
    float4 v = *(const float4*)(out2 + (size_t)b * Dd + tid * 4);
    unsigned* p = (unsigned*)(xnbf + (size_t)b * Dd + tid * 4);
    p[0] = cvt2bf(v.x * r, v.y * r);
    p[1] = cvt2bf(v.z * r, v.w * r);
}

// ---------------------------------------------------------------------------
// K3: e[b][n] = exp(xn[b,:] . embed[n,:]) via bf16 MFMA, LDS-staged operands.
// grid(782): 64 n x 64 b per block, 4 waves (16 n each). K chunked by 64,
// double-buffered: embed tile staged with contiguous 256-B segments (fixes
// the round-2 address-divergence stall); fragments via ds_read_b128.
// ---------------------------------------------------------------------------
__global__ __launch_bounds__(256, 1)
void k3_logits_mfma(const float* __restrict__ embed,
                    const unsigned short* __restrict__ xnbf,
                    float* __restrict__ out,
                    float* __restrict__ partials)
{
    const int tid  = threadIdx.x;
    const int wave = tid >> 6, lane = tid & 63;
    const int quad = lane >> 4, col = lane & 15;
    const int n0   = blockIdx.x * 64;

    __shared__ __align__(16) unsigned short bt[2][64 * 72];
    __shared__ __align__(16) unsigned short at[2][64 * 72];
    __shared__ float bpart[4][64];

    const floatx4 zz = {0.f, 0.f, 0.f, 0.f};
    floatx4 acc[4] = {zz, zz, zz, zz};

    // ---- stage chunk 0 ----
    {
        #pragma unroll
        for (int j = 0; j < 4; ++j) {
            int idx = tid + j * 256;
            int row = idx >> 4, c4 = idx & 15;
            int gn = n0 + row; if (gn >= NC) gn = NC - 1;
            float4 v = *(const float4*)(embed + (size_t)gn * Dd + c4 * 4);
            *(uint2*)&bt[0][row * 72 + c4 * 4] =
                make_uint2(cvt2bf(v.x, v.y), cvt2bf(v.z, v.w));
        }
        #pragma unroll
        for (int j = 0; j < 2; ++j) {
            int idx = tid + j * 256;
            int row = idx >> 3, q = idx & 7;
            uint4 v = *(const uint4*)(xnbf + (size_t)row * Dd + q * 8);
            *(uint4*)&at[0][row * 72 + q * 8] = v;
        }
    }
    __syncthreads();

    for (int c = 0; c < 16; ++c) {
        const int cur = c & 1;
        float4 bv[4]; uint4 av[2];
        if (c < 15) {
            const int c0 = (c + 1) * 64;
            #pragma unroll
            for (int j = 0; j < 4; ++j) {
                int idx = tid + j * 256;
                int row = idx >> 4, c4 = idx & 15;
                int gn = n0 + row; if (gn >= NC) gn = NC - 1;
                bv[j] = *(const float4*)(embed + (size_t)gn * Dd + c0 + c4 * 4);
            }
            #pragma unroll
            for (int j = 0; j < 2; ++j) {
                int idx = tid + j * 256;
                av[j] = *(const uint4*)(xnbf + (size_t)(idx >> 3) * Dd + c0 + (idx & 7) * 8);
            }
        }

        #pragma unroll
        for (int ks = 0; ks < 2; ++ks) {
            frag_u bf;
            bf.s8 = *(const short8*)&bt[cur][(wave * 16 + col) * 72 + ks * 32 + quad * 8];
            frag_u af[4];
            #pragma unroll
            for (int s = 0; s < 4; ++s)
                af[s].s8 = *(const short8*)&at[cur][(s * 16 + col) * 72 + ks * 32 + quad * 8];
            #pragma unroll
            for (int s = 0; s < 4; ++s)
                acc[s] = __builtin_amdgcn_mfma_f32_16x16x32_bf16(
                    af[s].s8, bf.s8, acc[s], 0, 0, 0);
        }

        if (c < 15) {
            #pragma unroll
            for (int j = 0; j < 4; ++j) {
                int idx = tid + j * 256;
                int row = idx >> 4, c4 = idx & 15;
                *(uint2*)&bt[cur ^ 1][row * 72 + c4 * 4] =
                    make_uint2(cvt2bf(bv[j].x, bv[j].y), cvt2bf(bv[j].z, bv[j].w));
            }
            #pragma unroll
            for (int j = 0; j < 2; ++j) {
                int idx = tid + j * 256;
                *(uint4*)&at[cur ^ 1][(idx >> 3) * 72 + (idx & 7) * 8] = av[j];
            }
            __syncthreads();
        }
    }

    // epilogue: exp, store, per-block partial sums
    const int n = n0 + wave * 16 + col;
    const bool vn = (n < NC);
    float e[4][4];
    #pragma unroll
    for (int s = 0; s < 4; ++s)
        #pragma unroll
        for (int r = 0; r < 4; ++r) {
            float v = vn ? __expf(acc[s][r]) : 0.f;
            e[s][r] = v;
            if (vn) out[(size_t)(s * 16 + quad * 4 + r) * NC + n] = v;
        }
    #pragma unroll
    for (int s = 0; s < 4; ++s)
        #pragma unroll
        for (int r = 0; r < 4; ++r) {
            float v = e[s][r];
            v += __shfl_xor(v, 1, 64); v += __shfl_xor(v, 2, 64);
            v += __shfl_xor(v, 4, 64); v += __shfl_xor(v, 8, 64);
            if (col == 0) bpart[wave][s * 16 + quad * 4 + r] = v;
        }
    __syncthreads();
    if (tid < 64)
        partials[(size_t)blockIdx.x * 64 + tid] =
            bpart[0][tid] + bpart[1][tid] + bpart[2][tid] + bpart[3][tid];
}

// ---------------------------------------------------------------------------
// K3b: rsum[b] = 1 / sum_k partials[k][b]   (256 thr: 4-way k-slice)
// ---------------------------------------------------------------------------
__global__ void k3b_reduce(const float* __restrict__ partials,
                           float* __restrict__ rsum)
{
    const int tid = threadIdx.x;
    const int b = tid & 63, s = tid >> 6;
    float acc = 0.f;
    for (int k = s; k < NBLK3; k += 4)
        acc += partials[(size_t)k * 64 + b];
    __shared__ float red[4][64];
    red[s][b] = acc;
    __syncthreads();
    if (tid < 64)
        rsum[tid] = 1.f / (red[0][tid] + red[1][tid] + red[2][tid] + red[3][tid]);
}

// ---------------------------------------------------------------------------
// K4: out[b][n] *= rsum[b]
// ---------------------------------------------------------------------------
__global__ __launch_bounds__(256)
void k4_scale(float* __restrict__ out, const float* __restrict__ rsum)
{
    const int b  = blockIdx.y;
    const int n4 = (blockIdx.x * 256 + threadIdx.x) * 4;
    if (n4 >= NC) return;
    const float r = rsum[b];
    float4* p = (float4*)(out + (size_t)b * NC + n4);
    float4 v = *p;
    v.x *= r; v.y *= r; v.z *= r; v.w *= r;
    *p = v;
}

extern "C" void kernel_launch(void* const* d_in, const int* in_sizes, int n_in,
                              void* d_out, int out_size, void* d_ws, size_t ws_size,
                              hipStream_t stream)
{
    const float* x      = (const float*)d_in[0];
    const float* embed  = (const float*)d_in[1];
    const float* conv_w = (const float*)d_in[2];
    const float* conv_b = (const float*)d_in[3];
    const float* lin_w  = (const float*)d_in[4];
    const float* lin_b  = (const float*)d_in[5];
    float* out = (float*)d_out;
    float* ws  = (float*)d_ws;

    float*    pooled     = ws;                         // 65536
    float*    normsq     = ws + 65536;                 // 64
    float*    out2       = ws + 65536 + 64;            // 65536
    unsigned short* xnbf = (unsigned short*)(ws + 131136); // 65536 bf16
    float*    partials   = ws + 131136 + 32768;        // 782*64 = 50048
    float*    rsum       = ws + 213952;                // 64

    hipMemsetAsync(normsq, 0, 64 * sizeof(float), stream);

    k1_conv_mfma<<<dim3(64, 4), 256, 0, stream>>>(x, conv_w, conv_b, pooled);
    k2_linear<<<dim3(4096), 256, 0, stream>>>(pooled, lin_w, lin_b, out2, normsq);
    k2b_norm_cvt<<<dim3(64), 256, 0, stream>>>(out2, normsq, xnbf);
    k3_logits_mfma<<<dim3(NBLK3), 256, 0, stream>>>(embed, xnbf, out, partials);
    k3b_reduce<<<dim3(1), 256, 0, stream>>>(partials, rsum);
    k4_scale<<<dim3(49, 64), 256, 0, stream>>>(out, rsum);
}

// Round 4
// 434.178 us; speedup vs baseline: 2.5702x; 1.2171x over previous
//
#include <hip/hip_runtime.h>
#include <hip/hip_bf16.h>
#include <math.h>

#define Bb 64
#define Ll 2048
#define Ff 100
#define Dd 1024
#define NC 50000
#define NBLK3 782   // ceil(50000/64)

typedef __attribute__((ext_vector_type(8))) short short8;
typedef __attribute__((ext_vector_type(4))) float floatx4;

union frag_u { short8 s8; unsigned u[4]; uint4 u4; };

__device__ __forceinline__ unsigned cvt2bf(float x, float y) {
    __hip_bfloat162 h = __float22bfloat162_rn(make_float2(x, y));
    unsigned r; __builtin_memcpy(&r, &h, 4); return r;
}

// order-preserving float -> uint map (for atomicMax pooling)
__device__ __forceinline__ unsigned encf(float f) {
    unsigned u = __float_as_uint(f);
    return (u & 0x80000000u) ? ~u : (u | 0x80000000u);
}

// ---------------------------------------------------------------------------
// K0: pack conv_w -> bf16 MFMA B-fragment order:
// wp[(((ds*4+kc)*4+quad)*16+col)*8 + j] = bf16(conv_w[ds*16+col][kc*32+quad*8+j])
// (zero-padded past k=100). One wave B-frag load = contiguous 1 KB segment.
// ---------------------------------------------------------------------------
__global__ __launch_bounds__(256)
void k0_pack_w(const float* __restrict__ conv_w, unsigned short* __restrict__ wp)
{
    const int t = blockIdx.x * 256 + threadIdx.x;   // 16384
    const int col = t & 15, quad = (t >> 4) & 3, kc = (t >> 6) & 3, ds = t >> 8;
    const int d = ds * 16 + col, k0 = kc * 32 + quad * 8;
    unsigned short v[8];
    #pragma unroll
    for (int j = 0; j < 8; ++j) {
        int k = k0 + j;
        float f = (k < Ff) ? conv_w[(size_t)d * Ff + k] : 0.f;
        unsigned u = cvt2bf(f, 0.f);
        v[j] = (unsigned short)(u & 0xFFFFu);
    }
    *(uint4*)(wp + (size_t)t * 8) = *(uint4*)v;
}

// ---------------------------------------------------------------------------
// K1: max_l (x[b,l,:] . conv_w[d,:]) via bf16 MFMA.
// grid(64 b, 16 lw) = 1024 blocks. Block = 128 l x ALL 1024 d; x tile staged
// to LDS ONCE (34.8 KB, single __syncthreads). Wave owns 256 d; B-frags from
// packed wp (coalesced, L2-hot). Cross-lw max via atomicMax(encoded).
// ---------------------------------------------------------------------------
__global__ __launch_bounds__(256, 2)
void k1_conv_mfma(const float* __restrict__ x,
                  const unsigned short* __restrict__ wp,
                  unsigned* __restrict__ pooled_enc)
{
    const int b    = blockIdx.x;
    const int lw   = blockIdx.y;
    const int tid  = threadIdx.x;
    const int wave = tid >> 6, lane = tid & 63;
    const int quad = lane >> 4, col = lane & 15;

    __shared__ __align__(16) unsigned short xs[128 * 136];

    // zero k-pad (cols 100..135)
    for (int i = tid; i < 128 * 18; i += 256) {
        int row = i / 18, c = i % 18;
        *(unsigned*)&xs[row * 136 + 100 + c * 2] = 0u;
    }
    // stage x[b, lw*128..+127][0..99] -> bf16
    {
        const float* xw = x + ((size_t)b * Ll + (size_t)lw * 128) * Ff;
        #pragma unroll
        for (int j = 0; j < 13; ++j) {
            int idx = tid + j * 256;
            if (idx < 3200) {
                float4 v = *(const float4*)(xw + idx * 4);
                int row = idx / 25, c4 = idx % 25;
                *(uint2*)&xs[row * 136 + c4 * 4] =
                    make_uint2(cvt2bf(v.x, v.y), cvt2bf(v.z, v.w));
            }
        }
    }
    __syncthreads();

    const floatx4 zz = {0.f, 0.f, 0.f, 0.f};
    float mx[16];
    #pragma unroll
    for (int i = 0; i < 16; ++i) mx[i] = -INFINITY;

    #pragma unroll 1
    for (int g = 0; g < 4; ++g) {
        // B-fragments for 4 d-subtiles x 4 kc (coalesced 1KB segments)
        frag_u B[4][4];
        #pragma unroll
        for (int i = 0; i < 4; ++i) {
            const int ds = wave * 16 + g * 4 + i;
            #pragma unroll
            for (int kc = 0; kc < 4; ++kc)
                B[i][kc].u4 = *(const uint4*)(wp +
                    ((size_t)(ds * 4 + kc) * 64 + lane) * 8);
        }
        #pragma unroll 1
        for (int m = 0; m < 8; ++m) {
            frag_u A[4];
            #pragma unroll
            for (int kc = 0; kc < 4; ++kc)
                A[kc].s8 = *(const short8*)&xs[(m * 16 + col) * 136 + kc * 32 + quad * 8];
            floatx4 acc[4];
            #pragma unroll
            for (int i = 0; i < 4; ++i)
                acc[i] = __builtin_amdgcn_mfma_f32_16x16x32_bf16(A[0].s8, B[i][0].s8, zz, 0, 0, 0);
            #pragma unroll
            for (int kc = 1; kc < 4; ++kc)
                #pragma unroll
                for (int i = 0; i < 4; ++i)
                    acc[i] = __builtin_amdgcn_mfma_f32_16x16x32_bf16(A[kc].s8, B[i][kc].s8, acc[i], 0, 0, 0);
            #pragma unroll
            for (int i = 0; i < 4; ++i)
                #pragma unroll
                for (int r = 0; r < 4; ++r)
                    mx[g * 4 + i] = fmaxf(mx[g * 4 + i], acc[i][r]);
        }
    }

    #pragma unroll
    for (int gi = 0; gi < 16; ++gi) {
        float mm = mx[gi];
        mm = fmaxf(mm, __shfl_xor(mm, 16, 64));
        mm = fmaxf(mm, __shfl_xor(mm, 32, 64));
        if (quad == 0) {
            const int d = (wave * 16 + gi) * 16 + col;
            atomicMax(&pooled_enc[(size_t)b * Dd + d], encf(mm));
        }
    }
}

// ---------------------------------------------------------------------------
// K1b: decode encoded max, + conv_b, elu (in-place uint -> float)
// ---------------------------------------------------------------------------
__global__ __launch_bounds__(256)
void k1b_decode(unsigned* __restrict__ pooled_enc,
                const float* __restrict__ conv_b)
{
    const int i = blockIdx.x * 256 + threadIdx.x;   // 65536
    unsigned e = pooled_enc[i];
    unsigned ub = (e & 0x80000000u) ? (e ^ 0x80000000u) : ~e;
    float m = __uint_as_float(ub) + conv_b[i & (Dd - 1)];
    ((float*)pooled_enc)[i] = (m > 0.f) ? m : expm1f(m);
}

// ---------------------------------------------------------------------------
// K2: out2[b][d] = relu(pooled[b,:] . lin_w[d,:] + lin_b[d]); normsq[b] += o^2
// grid(4096) = 64 b x 64 dtiles of 16 d; 16 k-lanes/dot, coalesced 256 B segs.
// ---------------------------------------------------------------------------
__global__ __launch_bounds__(256)
void k2_linear(const float* __restrict__ pooled,
               const float* __restrict__ lin_w,
               const float* __restrict__ lin_b,
               float* __restrict__ out2,
               float* __restrict__ normsq)
{
    const int bx = blockIdx.x;
    const int b = bx >> 6, dt = bx & 63;
    const int tid = threadIdx.x;
    const int dl = tid >> 4, kq = tid & 15;
    const int d = dt * 16 + dl;
    const float* wr = lin_w + (size_t)d * Dd;
    const float* pr = pooled + (size_t)b * Dd;
    float acc = 0.f;
    #pragma unroll
    for (int i = 0; i < 16; ++i) {
        const int off = i * 64 + kq * 4;
        float4 wv = *(const float4*)(wr + off);
        float4 pv = *(const float4*)(pr + off);
        acc = fmaf(wv.x, pv.x, fmaf(wv.y, pv.y, fmaf(wv.z, pv.z, fmaf(wv.w, pv.w, acc))));
    }
    acc += __shfl_xor(acc, 1, 64);
    acc += __shfl_xor(acc, 2, 64);
    acc += __shfl_xor(acc, 4, 64);
    acc += __shfl_xor(acc, 8, 64);
    float ss = 0.f;
    if (kq == 0) {
        float o = fmaxf(acc + lin_b[d], 0.f);
        out2[(size_t)b * Dd + d] = o;
        ss = o * o;
    }
    ss += __shfl_xor(ss, 16, 64);
    ss += __shfl_xor(ss, 32, 64);
    __shared__ float wsum[4];
    if ((tid & 63) == 0) wsum[tid >> 6] = ss;
    __syncthreads();
    if (tid == 0)
        atomicAdd(&normsq[b], wsum[0] + wsum[1] + wsum[2] + wsum[3]);
}

// ---------------------------------------------------------------------------
// K2b: xnbf[b][d] = bf16( out2[b][d] / max(||out2[b]||, eps) )
// ---------------------------------------------------------------------------
__global__ __launch_bounds__(256)
void k2b_norm_cvt(const float* __restrict__ out2,
                  const float* __restrict__ normsq,
                  unsigned short* __restrict__ xnbf)
{
    const int b = blockIdx.x, tid = threadIdx.x;
    const float r = 1.f / fmaxf(sqrtf(normsq[b]), 1e-12f);
    float4 v = *(const float4*)(out2 + (size_t)b * Dd + tid * 4);
    unsigned* p = (unsigned*)(xnbf + (size_t)b * Dd + tid * 4);
    p[0] = cvt2bf(v.x * r, v.y * r);
    p[1] = cvt2bf(v.z * r, v.w * r);
}

// ---------------------------------------------------------------------------
// K3: e[b][n] = exp(xn[b,:] . embed[n,:]) via bf16 MFMA, LDS double-buffered.
// grid(782): 64 n x 64 b per block, 4 waves.
// ---------------------------------------------------------------------------
__global__ __launch_bounds__(256, 1)
void k3_logits_mfma(const float* __restrict__ embed,
                    const unsigned short* __restrict__ xnbf,
                    float* __restrict__ out,
                    float* __restrict__ partials)
{
    const int tid  = threadIdx.x;
    const int wave = tid >> 6, lane = tid & 63;
    const int quad = lane >> 4, col = lane & 15;
    const int n0   = blockIdx.x * 64;

    __shared__ __align__(16) unsigned short bt[2][64 * 72];
    __shared__ __align__(16) unsigned short at[2][64 * 72];
    __shared__ float bpart[4][64];

    const floatx4 zz = {0.f, 0.f, 0.f, 0.f};
    floatx4 acc[4] = {zz, zz, zz, zz};

    {
        #pragma unroll
        for (int j = 0; j < 4; ++j) {
            int idx = tid + j * 256;
            int row = idx >> 4, c4 = idx & 15;
            int gn = n0 + row; if (gn >= NC) gn = NC - 1;
            float4 v = *(const float4*)(embed + (size_t)gn * Dd + c4 * 4);
            *(uint2*)&bt[0][row * 72 + c4 * 4] =
                make_uint2(cvt2bf(v.x, v.y), cvt2bf(v.z, v.w));
        }
        #pragma unroll
        for (int j = 0; j < 2; ++j) {
            int idx = tid + j * 256;
            int row = idx >> 3, q = idx & 7;
            uint4 v = *(const uint4*)(xnbf + (size_t)row * Dd + q * 8);
            *(uint4*)&at[0][row * 72 + q * 8] = v;
        }
    }
    __syncthreads();

    for (int c = 0; c < 16; ++c) {
        const int cur = c & 1;
        float4 bv[4]; uint4 av[2];
        if (c < 15) {
            const int c0 = (c + 1) * 64;
            #pragma unroll
            for (int j = 0; j < 4; ++j) {
                int idx = tid + j * 256;
                int row = idx >> 4, c4 = idx & 15;
                int gn = n0 + row; if (gn >= NC) gn = NC - 1;
                bv[j] = *(const float4*)(embed + (size_t)gn * Dd + c0 + c4 * 4);
            }
            #pragma unroll
            for (int j = 0; j < 2; ++j) {
                int idx = tid + j * 256;
                av[j] = *(const uint4*)(xnbf + (size_t)(idx >> 3) * Dd + c0 + (idx & 7) * 8);
            }
        }

        #pragma unroll
        for (int ks = 0; ks < 2; ++ks) {
            frag_u bf;
            bf.s8 = *(const short8*)&bt[cur][(wave * 16 + col) * 72 + ks * 32 + quad * 8];
            frag_u af[4];
            #pragma unroll
            for (int s = 0; s < 4; ++s)
                af[s].s8 = *(const short8*)&at[cur][(s * 16 + col) * 72 + ks * 32 + quad * 8];
            #pragma unroll
            for (int s = 0; s < 4; ++s)
                acc[s] = __builtin_amdgcn_mfma_f32_16x16x32_bf16(
                    af[s].s8, bf.s8, acc[s], 0, 0, 0);
        }

        if (c < 15) {
            #pragma unroll
            for (int j = 0; j < 4; ++j) {
                int idx = tid + j * 256;
                int row = idx >> 4, c4 = idx & 15;
                *(uint2*)&bt[cur ^ 1][row * 72 + c4 * 4] =
                    make_uint2(cvt2bf(bv[j].x, bv[j].y), cvt2bf(bv[j].z, bv[j].w));
            }
            #pragma unroll
            for (int j = 0; j < 2; ++j) {
                int idx = tid + j * 256;
                *(uint4*)&at[cur ^ 1][(idx >> 3) * 72 + (idx & 7) * 8] = av[j];
            }
            __syncthreads();
        }
    }

    const int n = n0 + wave * 16 + col;
    const bool vn = (n < NC);
    float e[4][4];
    #pragma unroll
    for (int s = 0; s < 4; ++s)
        #pragma unroll
        for (int r = 0; r < 4; ++r) {
            float v = vn ? __expf(acc[s][r]) : 0.f;
            e[s][r] = v;
            if (vn) out[(size_t)(s * 16 + quad * 4 + r) * NC + n] = v;
        }
    #pragma unroll
    for (int s = 0; s < 4; ++s)
        #pragma unroll
        for (int r = 0; r < 4; ++r) {
            float v = e[s][r];
            v += __shfl_xor(v, 1, 64); v += __shfl_xor(v, 2, 64);
            v += __shfl_xor(v, 4, 64); v += __shfl_xor(v, 8, 64);
            if (col == 0) bpart[wave][s * 16 + quad * 4 + r] = v;
        }
    __syncthreads();
    if (tid < 64)
        partials[(size_t)blockIdx.x * 64 + tid] =
            bpart[0][tid] + bpart[1][tid] + bpart[2][tid] + bpart[3][tid];
}

// ---------------------------------------------------------------------------
// K3b: rsum[b] = 1 / sum_k partials[k][b]   grid(64): one b per block
// ---------------------------------------------------------------------------
__global__ __launch_bounds__(256)
void k3b_reduce(const float* __restrict__ partials,
                float* __restrict__ rsum)
{
    const int b = blockIdx.x, tid = threadIdx.x;
    float a = 0.f;
    for (int k = tid; k < NBLK3; k += 256)
        a += partials[(size_t)k * 64 + b];
    a += __shfl_xor(a, 1, 64);  a += __shfl_xor(a, 2, 64);
    a += __shfl_xor(a, 4, 64);  a += __shfl_xor(a, 8, 64);
    a += __shfl_xor(a, 16, 64); a += __shfl_xor(a, 32, 64);
    __shared__ float wsum[4];
    if ((tid & 63) == 0) wsum[tid >> 6] = a;
    __syncthreads();
    if (tid == 0)
        rsum[b] = 1.f / (wsum[0] + wsum[1] + wsum[2] + wsum[3]);
}

// ---------------------------------------------------------------------------
// K4: out[b][n] *= rsum[b]
// ---------------------------------------------------------------------------
__global__ __launch_bounds__(256)
void k4_scale(float* __restrict__ out, const float* __restrict__ rsum)
{
    const int b  = blockIdx.y;
    const int n4 = (blockIdx.x * 256 + threadIdx.x) * 4;
    if (n4 >= NC) return;
    const float r = rsum[b];
    float4* p = (float4*)(out + (size_t)b * NC + n4);
    float4 v = *p;
    v.x *= r; v.y *= r; v.z *= r; v.w *= r;
    *p = v;
}

extern "C" void kernel_launch(void* const* d_in, const int* in_sizes, int n_in,
                              void* d_out, int out_size, void* d_ws, size_t ws_size,
                              hipStream_t stream)
{
    const float* x      = (const float*)d_in[0];
    const float* embed  = (const float*)d_in[1];
    const float* conv_w = (const float*)d_in[2];
    const float* conv_b = (const float*)d_in[3];
    const float* lin_w  = (const float*)d_in[4];
    const float* lin_b  = (const float*)d_in[5];
    float* out = (float*)d_out;
    float* ws  = (float*)d_ws;

    unsigned short* wpack = (unsigned short*)ws;       // 131072 shorts = 65536 f
    unsigned* pooled_enc  = (unsigned*)(ws + 65536);   // 65536 (aliased fp32 after k1b)
    float*    pooled      = ws + 65536;
    float*    normsq      = ws + 131072;               // 64
    float*    out2        = ws + 131136;               // 65536
    unsigned short* xnbf  = (unsigned short*)(ws + 196672); // 65536 bf16
    float*    partials    = ws + 196672 + 32768;       // 50048
    float*    rsum        = ws + 279488;               // 64

    // zero pooled_enc + normsq (contiguous)
    hipMemsetAsync(ws + 65536, 0, (65536 + 64) * sizeof(float), stream);

    k0_pack_w<<<dim3(64), 256, 0, stream>>>(conv_w, wpack);
    k1_conv_mfma<<<dim3(64, 16), 256, 0, stream>>>(x, wpack, pooled_enc);
    k1b_decode<<<dim3(256), 256, 0, stream>>>(pooled_enc, conv_b);
    k2_linear<<<dim3(4096), 256, 0, stream>>>(pooled, lin_w, lin_b, out2, normsq);
    k2b_norm_cvt<<<dim3(64), 256, 0, stream>>>(out2, normsq, xnbf);
    k3_logits_mfma<<<dim3(NBLK3), 256, 0, stream>>>(embed, xnbf, out, partials);
    k3b_reduce<<<dim3(64), 256, 0, stream>>>(partials, rsum);
    k4_scale<<<dim3(49, 64), 256, 0, stream>>>(out, rsum);
}